// Round 3
// baseline (1346.510 us; speedup 1.0000x reference)
//
#include <hip/hip_runtime.h>

#define B_  8
#define S1_ 2048
#define S2_ 2048
#define H_  1024

typedef unsigned short u16;
typedef __attribute__((ext_vector_type(8))) short short8;   // 8 bf16 (4 VGPRs)
typedef __attribute__((ext_vector_type(4))) float f32x4;

__device__ __forceinline__ float b2f(u16 u) {
  union { unsigned int i; float f; } v; v.i = ((unsigned int)u) << 16; return v.f;
}
__device__ __forceinline__ u16 f2b(float f) {
  union { float f; unsigned int i; } v; v.f = f;
  unsigned int r = v.i + 0x7fffu + ((v.i >> 16) & 1u);   // RNE
  return (u16)(r >> 16);
}

// split fp32 x -> hi(bf16) + lo(bf16), x ~= hi + lo to ~2^-17 rel
__device__ __forceinline__ void cvt8_split(float4 va, float4 vb, short8* hi, short8* lo) {
  float x[8] = {va.x, va.y, va.z, va.w, vb.x, vb.y, vb.z, vb.w};
  short8 h, l;
#pragma unroll
  for (int e = 0; e < 8; ++e) {
    u16 hb = f2b(x[e]);
    h[e] = (short)hb;
    l[e] = (short)f2b(x[e] - b2f(hb));   // residual; subtraction exact (Sterbenz)
  }
  *hi = h; *lo = l;
}
__device__ __forceinline__ short8 cvt8(float4 va, float4 vb) {
  float x[8] = {va.x, va.y, va.z, va.w, vb.x, vb.y, vb.z, vb.w};
  short8 h;
#pragma unroll
  for (int e = 0; e < 8; ++e) h[e] = (short)f2b(x[e]);
  return h;
}

// C[m,n] = sum_k A[m,k] * B'[k,n], all fp32 in HBM, bf16 MFMA internally.
// BTR=0: B is [N,K] row-major (ldb=K).  BTR=1: B is [K,N] row-major (ldb=N), transposed during staging.
// SPLIT=1: 3-pass hi/lo bf16 (~fp32-accurate).  DO_MASK: mask[b,n,m]!=0 -> C=-1e30. ADD_BIAS: +bias[n].
template<bool ADD_BIAS, bool DO_MASK, bool SPLIT, bool BTR>
__global__ __launch_bounds__(256)
void gemm_k(const float* __restrict__ A, long sA,
            const float* __restrict__ B, long sB, int ldb,
            const float* __restrict__ bias,
            const int* __restrict__ mask, long sMask, int mask_ld,
            float* __restrict__ C, long sC, int ldc, int K)
{
  __shared__ __align__(16) union {
    struct { u16 hi[2][128 * 32]; u16 lo[2][128 * 32]; } t;   // 32 KB
    unsigned char m[128][128];                                 // mask tile (epilogue)
  } sh;

  const int t    = threadIdx.x;
  const int lane = t & 63;
  const int wv   = t >> 6;
  const int wm   = wv >> 1, wn = wv & 1;
  const int batch = blockIdx.z;
  const int m0 = blockIdx.x * 128;
  const int n0 = blockIdx.y * 128;

  const float* Ab = A + (long)batch * sA + (long)m0 * K;
  const float* Bb = B + (long)batch * sB + (BTR ? (long)n0 : (long)n0 * ldb);

  f32x4 acc[4][4];
#pragma unroll
  for (int i = 0; i < 4; ++i)
#pragma unroll
    for (int j = 0; j < 4; ++j)
      acc[i][j] = (f32x4){0.f, 0.f, 0.f, 0.f};

  // A-tile chunks: 8 consecutive k per chunk; c=t covers rows 0..63, c=t+256 rows 64..127
  const int c0 = t,       r0 = c0 >> 2, o0 = (c0 & 3) * 8;
  const int c1 = t + 256, r1 = c1 >> 2, o1 = (c1 & 3) * 8;

  const int fr = lane & 15;     // fragment row (m or n within 16)
  const int kg = lane >> 4;     // k-group 0..3 (8 bf16 each)

  for (int kc = 0; kc < K; kc += 32) {
    // ---- global loads (fp32), hoisted above barrier ----
    float4 a00 = *(const float4*)(Ab + (long)r0 * K + kc + o0);
    float4 a01 = *(const float4*)(Ab + (long)r0 * K + kc + o0 + 4);
    float4 a10 = *(const float4*)(Ab + (long)r1 * K + kc + o1);
    float4 a11 = *(const float4*)(Ab + (long)r1 * K + kc + o1 + 4);
    float4 bb[4];
    if (BTR) {
      // B tile rows kc..kc+31, cols n0..n0+127: chunk cb -> krow=cb>>5, nc4=(cb&31)*4
#pragma unroll
      for (int q = 0; q < 4; ++q) {
        int cb = t + 256 * q;
        int krow = cb >> 5, nc4 = (cb & 31) * 4;
        bb[q] = *(const float4*)(Bb + (long)(kc + krow) * ldb + nc4);
      }
    } else {
      bb[0] = *(const float4*)(Bb + (long)r0 * ldb + kc + o0);
      bb[1] = *(const float4*)(Bb + (long)r0 * ldb + kc + o0 + 4);
      bb[2] = *(const float4*)(Bb + (long)r1 * ldb + kc + o1);
      bb[3] = *(const float4*)(Bb + (long)r1 * ldb + kc + o1 + 4);
    }
    __syncthreads();   // prior iteration's ds_reads retired before overwrite

    if (SPLIT) {
      short8 h, l;
      cvt8_split(a00, a01, &h, &l);
      *(short8*)&sh.t.hi[0][c0 * 8] = h;  *(short8*)&sh.t.lo[0][c0 * 8] = l;
      cvt8_split(a10, a11, &h, &l);
      *(short8*)&sh.t.hi[0][c1 * 8] = h;  *(short8*)&sh.t.lo[0][c1 * 8] = l;
      cvt8_split(bb[0], bb[1], &h, &l);
      *(short8*)&sh.t.hi[1][c0 * 8] = h;  *(short8*)&sh.t.lo[1][c0 * 8] = l;
      cvt8_split(bb[2], bb[3], &h, &l);
      *(short8*)&sh.t.hi[1][c1 * 8] = h;  *(short8*)&sh.t.lo[1][c1 * 8] = l;
    } else {
      *(short8*)&sh.t.hi[0][c0 * 8] = cvt8(a00, a01);
      *(short8*)&sh.t.hi[0][c1 * 8] = cvt8(a10, a11);
      if (BTR) {
#pragma unroll
        for (int q = 0; q < 4; ++q) {
          int cb = t + 256 * q;
          int krow = cb >> 5, nc4 = (cb & 31) * 4;
          float x[4] = {bb[q].x, bb[q].y, bb[q].z, bb[q].w};
#pragma unroll
          for (int e = 0; e < 4; ++e)
            sh.t.hi[1][(nc4 + e) * 32 + krow] = f2b(x[e]);   // [n][k] transposed store
        }
      } else {
        *(short8*)&sh.t.hi[1][c0 * 8] = cvt8(bb[0], bb[1]);
        *(short8*)&sh.t.hi[1][c1 * 8] = cvt8(bb[2], bb[3]);
      }
    }
    __syncthreads();

    short8 afh[4], bfh[4];
#pragma unroll
    for (int i = 0; i < 4; ++i)
      afh[i] = *(const short8*)&sh.t.hi[0][(wm * 64 + i * 16 + fr) * 32 + kg * 8];
#pragma unroll
    for (int j = 0; j < 4; ++j)
      bfh[j] = *(const short8*)&sh.t.hi[1][(wn * 64 + j * 16 + fr) * 32 + kg * 8];

    if (SPLIT) {
      short8 afl[4], bfl[4];
#pragma unroll
      for (int i = 0; i < 4; ++i)
        afl[i] = *(const short8*)&sh.t.lo[0][(wm * 64 + i * 16 + fr) * 32 + kg * 8];
#pragma unroll
      for (int j = 0; j < 4; ++j)
        bfl[j] = *(const short8*)&sh.t.lo[1][(wn * 64 + j * 16 + fr) * 32 + kg * 8];
#pragma unroll
      for (int i = 0; i < 4; ++i)
#pragma unroll
        for (int j = 0; j < 4; ++j) {
          acc[i][j] = __builtin_amdgcn_mfma_f32_16x16x32_bf16(afh[i], bfh[j], acc[i][j], 0, 0, 0);
          acc[i][j] = __builtin_amdgcn_mfma_f32_16x16x32_bf16(afh[i], bfl[j], acc[i][j], 0, 0, 0);
          acc[i][j] = __builtin_amdgcn_mfma_f32_16x16x32_bf16(afl[i], bfh[j], acc[i][j], 0, 0, 0);
        }
    } else {
#pragma unroll
      for (int i = 0; i < 4; ++i)
#pragma unroll
        for (int j = 0; j < 4; ++j)
          acc[i][j] = __builtin_amdgcn_mfma_f32_16x16x32_bf16(afh[i], bfh[j], acc[i][j], 0, 0, 0);
    }
  }

  if (DO_MASK) {
    __syncthreads();  // retire last fragment ds_reads before LDS reuse as mask tile
    const int* mb = mask + (long)batch * sMask;
#pragma unroll
    for (int it = 0; it < 16; ++it) {
      int ql = it * 8 + (t >> 5);       // q (col of C): mask row -> coalesced int4 reads
      int kl = (t & 31) * 4;            // k (row of C)
      int4 mv = *(const int4*)(mb + (long)(n0 + ql) * mask_ld + (m0 + kl));
      sh.m[kl + 0][ql] = (unsigned char)(mv.x != 0);
      sh.m[kl + 1][ql] = (unsigned char)(mv.y != 0);
      sh.m[kl + 2][ql] = (unsigned char)(mv.z != 0);
      sh.m[kl + 3][ql] = (unsigned char)(mv.w != 0);
    }
    __syncthreads();
  }

  float bv[4];
  if (ADD_BIAS) {
#pragma unroll
    for (int j = 0; j < 4; ++j)
      bv[j] = bias[n0 + wn * 64 + j * 16 + fr];
  }

#pragma unroll
  for (int i = 0; i < 4; ++i) {
#pragma unroll
    for (int r = 0; r < 4; ++r) {
      int row = wm * 64 + i * 16 + (lane >> 4) * 4 + r;   // C row = m  [m89/m91 layout]
      long gro = (long)batch * sC + (long)(m0 + row) * ldc + n0;
#pragma unroll
      for (int j = 0; j < 4; ++j) {
        int col = wn * 64 + j * 16 + fr;                  // C col = n
        float v = acc[i][j][r];
        if (ADD_BIAS) v += bv[j];
        if (DO_MASK && sh.m[row][col]) v = -1e30f;
        C[gro + col] = v;
      }
    }
  }
}

// one block per row: in-place softmax over S1 contiguous fp32
__global__ __launch_bounds__(256)
void softmax_rows(float* __restrict__ scores)
{
  const long row = blockIdx.x;
  float* p = scores + row * (long)S1_;
  const int t = threadIdx.x;
  const int lane = t & 63, wv = t >> 6;

  float4 v0 = *(const float4*)(p + t * 8);
  float4 v1 = *(const float4*)(p + t * 8 + 4);
  float x[8] = {v0.x, v0.y, v0.z, v0.w, v1.x, v1.y, v1.z, v1.w};

  float m = x[0];
#pragma unroll
  for (int q = 1; q < 8; ++q) m = fmaxf(m, x[q]);
#pragma unroll
  for (int o = 32; o; o >>= 1) m = fmaxf(m, __shfl_xor(m, o));
  __shared__ float rb[4], sb[4];
  if (lane == 0) rb[wv] = m;
  __syncthreads();
  m = fmaxf(fmaxf(rb[0], rb[1]), fmaxf(rb[2], rb[3]));

  float e[8]; float s = 0.f;
#pragma unroll
  for (int q = 0; q < 8; ++q) { e[q] = __expf(x[q] - m); s += e[q]; }
#pragma unroll
  for (int o = 32; o; o >>= 1) s += __shfl_xor(s, o);
  if (lane == 0) sb[wv] = s;
  __syncthreads();
  s = sb[0] + sb[1] + sb[2] + sb[3];
  float inv = 1.f / s;

  float4 w0, w1;
  w0.x = e[0] * inv; w0.y = e[1] * inv; w0.z = e[2] * inv; w0.w = e[3] * inv;
  w1.x = e[4] * inv; w1.y = e[5] * inv; w1.z = e[6] * inv; w1.w = e[7] * inv;
  *(float4*)(p + t * 8)     = w0;
  *(float4*)(p + t * 8 + 4) = w1;
}

extern "C" void kernel_launch(void* const* d_in, const int* in_sizes, int n_in,
                              void* d_out, int out_size, void* d_ws, size_t ws_size,
                              hipStream_t stream)
{
  const float* value = (const float*)d_in[0];
  const float* key   = (const float*)d_in[1];
  const float* query = (const float*)d_in[2];
  const int*   mask  = (const int*)d_in[3];
  const float* W     = (const float*)d_in[4];
  const float* bias  = (const float*)d_in[5];

  float* ctx = (float*)d_out;                       // [B,S2,H] fp32; holds q_proj until K5
  float* wts = ctx + (size_t)B_ * S2_ * H_;         // [B,S2,S1] fp32; holds scores pre-softmax
  float* qproj = ctx;                               // [B,S1,H] fp32 == ctx region exactly

  dim3 blk(256);

  // K1: q_proj = query @ W^T + b  (split-bf16 3-pass; M = B*S1 flattened) -> ctx region
  gemm_k<true, false, true, false><<<dim3((B_ * S1_) / 128, H_ / 128, 1), blk, 0, stream>>>(
      query, 0, W, 0, H_, bias, nullptr, 0, 0, qproj, 0, H_, H_);

  // K2: scores[b,s2,s1] = key[b] @ q_proj[b]^T, mask[b,s1,s2]!=0 -> -1e30  (split 3-pass)
  gemm_k<false, true, true, false><<<dim3(S2_ / 128, S1_ / 128, B_), blk, 0, stream>>>(
      key, (long)S2_ * H_, qproj, (long)S1_ * H_, H_, nullptr,
      mask, (long)S1_ * S2_, S2_, wts, (long)S2_ * S1_, S1_, H_);

  // K3: in-place row softmax over S1
  softmax_rows<<<dim3(B_ * S2_), blk, 0, stream>>>(wts);

  // K5: context[b,s2,h] = weights[b] @ value[b]  (plain bf16, B loaded [K][N] transposed in staging)
  gemm_k<false, false, false, true><<<dim3(S2_ / 128, H_ / 128, B_), blk, 0, stream>>>(
      wts, (long)S2_ * S1_, value, (long)S1_ * H_, H_, nullptr,
      nullptr, 0, 0, ctx, (long)S2_ * H_, H_, S1_);
}